// Round 2
// baseline (1338.140 us; speedup 1.0000x reference)
//
#include <hip/hip_runtime.h>
#include <hip/hip_bf16.h>
#include <stdint.h>

#define K_EMB 8192
#define D_DIM 256
#define N_ROWS 16384          // 8*2048
#define DECAYF 0.99f
#define OMDF 0.01f
#define EPSF 1e-5f
#define CCOST 0.25f

// ---- workspace byte offsets ----
#define OFF_PACKED 0u                    // u64[16384]  = 131072 B
#define OFF_COUNTS 131072u               // f32[8192]   = 32768 B
#define OFF_ENORM  163840u               // f32[8192]   = 32768 B
#define OFF_NSUM   196608u               // f32[1]
#define OFF_LOSSA  196864u               // f32[128]
#define OFF_ZNORM  197376u               // f32[16384]  = 65536 B
#define OFF_DW     262912u               // f32[8192*256] = 8388608 B
#define WS_NEED    (262912u + 8388608u)

// ---- output float offsets (outputs concatenated flat, fp32) ----
#define O_ZST  0
#define O_LOSS 4194304
#define O_CODE 4194305
#define O_EMB  4210689
#define O_NCS  6307841
#define O_EMAW 6316033

// =====================================================================
// Kernel A: row squared-norms. one wave per row, 4 rows per block.
// used for both emb (8192 rows) and z (16384 rows).
// =====================================================================
__global__ void rownorm_kernel(const float* __restrict__ src,
                               float* __restrict__ dst) {
    int wave = threadIdx.x >> 6;
    int lane = threadIdx.x & 63;
    int row  = blockIdx.x * 4 + wave;
    const float4 v = *reinterpret_cast<const float4*>(&src[(size_t)row * D_DIM + lane * 4]);
    float s = v.x * v.x + v.y * v.y + v.z * v.z + v.w * v.w;
    #pragma unroll
    for (int off = 32; off; off >>= 1) s += __shfl_down(s, off, 64);
    if (lane == 0) dst[row] = s;
}

// =====================================================================
// Kernel B: tiled fp32 GEMM (z @ emb^T) fused with argmin of
// score = fl(znorm+enorm) - 2*dot   (matches reference rounding order)
// BM=BN=128, BK=32, 256 threads, 8x8 microtile.
// Cross-block argmin via atomicMin on packed (key<<32 | idx).
// =====================================================================
#define BM 128
#define BN 128
#define BK 32
#define NT_PER_BLOCK 8    // each block scans 8*128 = 1024 codes

union ArgSMem {
    struct { float As[BK][BM]; float Bs[BK][BN]; } t;   // 32 KB
    unsigned long long red[BM][17];                      // 17408 B (reuse)
};

__launch_bounds__(256)
__global__ void argmin_kernel(const float* __restrict__ z,
                              const float* __restrict__ emb,
                              const float* __restrict__ enorm,
                              const float* __restrict__ znorm,
                              unsigned long long* __restrict__ best) {
    __shared__ ArgSMem sm;
    const int t  = threadIdx.x;
    const int tc = t & 15;
    const int tr = t >> 4;
    const int m0 = blockIdx.x * BM;

    float bestScore[8];
    int   bestIdx[8];
    #pragma unroll
    for (int i = 0; i < 8; ++i) { bestScore[i] = 3.4e38f; bestIdx[i] = 0x7fffffff; }

    // per-thread row norms (rows tr*8..tr*8+7 of this block's M-tile)
    float zn[8];
    #pragma unroll
    for (int i = 0; i < 8; ++i) zn[i] = znorm[m0 + tr * 8 + i];

    for (int nt = 0; nt < NT_PER_BLOCK; ++nt) {
        const int n0 = (blockIdx.y * NT_PER_BLOCK + nt) * BN;

        float acc[8][8];
        #pragma unroll
        for (int i = 0; i < 8; ++i)
            #pragma unroll
            for (int j = 0; j < 8; ++j) acc[i][j] = 0.f;

        for (int k0 = 0; k0 < D_DIM; k0 += BK) {
            // stage A (z tile) and B (emb tile), transposed into [BK][128]
            #pragma unroll
            for (int f = 0; f < 4; ++f) {
                int lin = f * 256 + t;        // float4 id 0..1023
                int row = lin >> 3;           // 0..127
                int c4  = lin & 7;            // 0..7
                float4 v = *reinterpret_cast<const float4*>(
                    &z[(size_t)(m0 + row) * D_DIM + k0 + c4 * 4]);
                sm.t.As[c4 * 4 + 0][row] = v.x;
                sm.t.As[c4 * 4 + 1][row] = v.y;
                sm.t.As[c4 * 4 + 2][row] = v.z;
                sm.t.As[c4 * 4 + 3][row] = v.w;
                float4 w = *reinterpret_cast<const float4*>(
                    &emb[(size_t)(n0 + row) * D_DIM + k0 + c4 * 4]);
                sm.t.Bs[c4 * 4 + 0][row] = w.x;
                sm.t.Bs[c4 * 4 + 1][row] = w.y;
                sm.t.Bs[c4 * 4 + 2][row] = w.z;
                sm.t.Bs[c4 * 4 + 3][row] = w.w;
            }
            __syncthreads();
            #pragma unroll
            for (int kk = 0; kk < BK; ++kk) {
                float4 a0 = *reinterpret_cast<const float4*>(&sm.t.As[kk][tr * 8]);
                float4 a1 = *reinterpret_cast<const float4*>(&sm.t.As[kk][tr * 8 + 4]);
                float4 b0 = *reinterpret_cast<const float4*>(&sm.t.Bs[kk][tc * 4]);
                float4 b1 = *reinterpret_cast<const float4*>(&sm.t.Bs[kk][64 + tc * 4]);
                float av[8] = {a0.x, a0.y, a0.z, a0.w, a1.x, a1.y, a1.z, a1.w};
                float bv[8] = {b0.x, b0.y, b0.z, b0.w, b1.x, b1.y, b1.z, b1.w};
                #pragma unroll
                for (int i = 0; i < 8; ++i)
                    #pragma unroll
                    for (int j = 0; j < 8; ++j)
                        acc[i][j] = fmaf(av[i], bv[j], acc[i][j]);
            }
            __syncthreads();
        }

        // epilogue: score = (znorm+enorm) - 2*dot ; fold into running best
        #pragma unroll
        for (int j = 0; j < 8; ++j) {
            int col = n0 + ((j < 4) ? (tc * 4 + j) : (64 + tc * 4 + (j - 4)));
            float en = enorm[col];
            #pragma unroll
            for (int i = 0; i < 8; ++i) {
                float sc = (zn[i] + en) - 2.f * acc[i][j];
                if (sc < bestScore[i] || (sc == bestScore[i] && col < bestIdx[i])) {
                    bestScore[i] = sc; bestIdx[i] = col;
                }
            }
        }
    }

    // cross-thread reduce: 16 candidates per row (one per tc), then atomicMin
    #pragma unroll
    for (int i = 0; i < 8; ++i) {
        unsigned int u   = __float_as_uint(bestScore[i]);
        unsigned int key = (u & 0x80000000u) ? ~u : (u | 0x80000000u);
        sm.red[tr * 8 + i][tc] =
            ((unsigned long long)key << 32) | (unsigned int)bestIdx[i];
    }
    __syncthreads();
    if (t < BM) {
        unsigned long long mn = sm.red[t][0];
        #pragma unroll
        for (int c = 1; c < 16; ++c) {
            unsigned long long v = sm.red[t][c];
            mn = (v < mn) ? v : mn;
        }
        atomicMin(&best[m0 + t], mn);
    }
}

// =====================================================================
// Kernel C: per-row assignment: z_st, codes, loss partials, counts, dw
// one block (256 threads) per z row
// =====================================================================
__global__ void assign_kernel(const float* __restrict__ z,
                              const float* __restrict__ emb,
                              const unsigned long long* __restrict__ best,
                              float* __restrict__ out_zst,
                              float* __restrict__ out_codes,
                              float* __restrict__ dw,
                              float* __restrict__ counts,
                              float* __restrict__ loss_arr) {
    const int n = blockIdx.x;
    const int d = threadIdx.x;
    const int idx = (int)(best[n] & 0xffffffffull);

    float zv = z[(size_t)n * D_DIM + d];
    float ev = emb[(size_t)idx * D_DIM + d];
    float st = zv + (ev - zv);            // z + (z_q - z), literal fp32 order
    out_zst[(size_t)n * D_DIM + d] = st;

    float diff = ev - zv;
    float l = diff * diff;
    #pragma unroll
    for (int off = 32; off; off >>= 1) l += __shfl_down(l, off, 64);
    __shared__ float r4[4];
    if ((d & 63) == 0) r4[d >> 6] = l;
    __syncthreads();

    atomicAdd(&dw[(size_t)idx * D_DIM + d], zv);
    if (d == 0) {
        atomicAdd(&counts[idx], 1.0f);
        out_codes[n] = (float)idx;
        atomicAdd(&loss_arr[n & 127], r4[0] + r4[1] + r4[2] + r4[3]);
    }
}

// =====================================================================
// Kernel D1: new_cluster_size + sum(new_cluster_size) -> nsum
// =====================================================================
__global__ void ema_cs_kernel(const float* __restrict__ ema_cs,
                              const float* __restrict__ counts,
                              float* __restrict__ out_ncs,
                              float* __restrict__ nsum) {
    const int k = blockIdx.x * 256 + threadIdx.x;
    float v = ema_cs[k] * DECAYF + OMDF * counts[k];
    out_ncs[k] = v;
    float s = v;
    #pragma unroll
    for (int off = 32; off; off >>= 1) s += __shfl_down(s, off, 64);
    __shared__ float r4[4];
    if ((threadIdx.x & 63) == 0) r4[threadIdx.x >> 6] = s;
    __syncthreads();
    if (threadIdx.x == 0) atomicAdd(nsum, r4[0] + r4[1] + r4[2] + r4[3]);
}

// =====================================================================
// Kernel D2: new_ema_w, new_embedding, and the loss scalar
// one block per code row
// =====================================================================
__global__ void finalize_kernel(const float* __restrict__ ema_w,
                                const float* __restrict__ dw,
                                const float* __restrict__ out_ncs,
                                const float* __restrict__ nsum,
                                const float* __restrict__ loss_arr,
                                float* __restrict__ out_emb,
                                float* __restrict__ out_emaw,
                                float* __restrict__ out_loss) {
    const int k = blockIdx.x;
    const int d = threadIdx.x;
    const float n   = *nsum;
    const float ncs = out_ncs[k];
    const float cs  = (ncs + EPSF) / (n + (float)K_EMB * EPSF) * n;
    const size_t o  = (size_t)k * D_DIM + d;
    float w = ema_w[o] * DECAYF + OMDF * dw[o];
    out_emaw[o] = w;
    out_emb[o]  = w / cs;
    if (k == 0 && d == 0) {
        float s = 0.f;
        #pragma unroll
        for (int i = 0; i < 128; ++i) s += loss_arr[i];
        *out_loss = CCOST * s / (float)((size_t)N_ROWS * D_DIM);
    }
}

// =====================================================================
extern "C" void kernel_launch(void* const* d_in, const int* in_sizes, int n_in,
                              void* d_out, int out_size, void* d_ws, size_t ws_size,
                              hipStream_t stream) {
    const float* z      = (const float*)d_in[0];
    const float* emb    = (const float*)d_in[1];
    const float* ema_cs = (const float*)d_in[2];
    const float* ema_w  = (const float*)d_in[3];
    float* out = (float*)d_out;

    char* ws = (char*)d_ws;
    unsigned long long* best = (unsigned long long*)(ws + OFF_PACKED);
    float* counts   = (float*)(ws + OFF_COUNTS);
    float* enorm    = (float*)(ws + OFF_ENORM);
    float* nsum     = (float*)(ws + OFF_NSUM);
    float* loss_arr = (float*)(ws + OFF_LOSSA);
    float* znorm    = (float*)(ws + OFF_ZNORM);
    float* dw       = (float*)(ws + OFF_DW);

    // init scratch every call (harness re-poisons ws)
    hipMemsetAsync(ws + OFF_COUNTS, 0, WS_NEED - OFF_COUNTS, stream);
    hipMemsetAsync(ws + OFF_PACKED, 0xFF, OFF_COUNTS, stream);  // best = UINT64_MAX

    rownorm_kernel<<<K_EMB / 4, 256, 0, stream>>>(emb, enorm);
    rownorm_kernel<<<N_ROWS / 4, 256, 0, stream>>>(z, znorm);

    dim3 grid_b(N_ROWS / BM, K_EMB / (BN * NT_PER_BLOCK));   // (128, 8)
    argmin_kernel<<<grid_b, 256, 0, stream>>>(z, emb, enorm, znorm, best);

    assign_kernel<<<N_ROWS, 256, 0, stream>>>(
        z, emb, best, out + O_ZST, out + O_CODE, dw, counts, loss_arr);

    ema_cs_kernel<<<K_EMB / 256, 256, 0, stream>>>(ema_cs, counts,
                                                   out + O_NCS, nsum);

    finalize_kernel<<<K_EMB, 256, 0, stream>>>(
        ema_w, dw, out + O_NCS, nsum, loss_arr,
        out + O_EMB, out + O_EMAW, out + O_LOSS);
}

// Round 7
// 367.411 us; speedup vs baseline: 3.6421x; 3.6421x over previous
//
#include <hip/hip_runtime.h>
#include <hip/hip_bf16.h>
#include <stdint.h>

#define K_EMB 8192
#define D_DIM 256
#define N_ROWS 16384          // 8*2048
#define DECAYF 0.99f
#define OMDF 0.01f
#define EPSF 1e-5f
#define CCOST 0.25f
#define NSTEP 8               // 256 / 32

// ---- workspace byte offsets ----
#define OFF_PACKED 0u                    // u64[16384]  = 131072 B
#define OFF_COUNTS 131072u               // f32[8192]
#define OFF_ENORM  163840u               // f32[8192]
#define OFF_NSUM   196608u               // f32[1] (+pad)
#define OFF_LOSSA  196864u               // f32[128] (+pad)
#define OFF_ZNORM  197376u               // f32[16384]
#define OFF_ZH     262912u               // bf16[16384*256] = 8 MB  (reused as dw after GEMM)
#define OFF_DW     262912u               // f32[8192*256]   = 8 MB  (alias of ZH)
#define OFF_ZL     8651520u              // 8 MB
#define OFF_EH     17040128u             // 4 MB
#define OFF_EL     21234432u             // 4 MB
// total ws need: 25428736 B

// ---- output float offsets (outputs concatenated flat, fp32) ----
#define O_ZST  0
#define O_LOSS 4194304
#define O_CODE 4194305
#define O_EMB  4210689
#define O_NCS  6307841
#define O_EMAW 6316033

typedef __bf16 bf16x8 __attribute__((ext_vector_type(8)));
typedef float  f32x4  __attribute__((ext_vector_type(4)));
typedef unsigned short us8 __attribute__((ext_vector_type(8)));

// =====================================================================
// async global->LDS 16B (wave-uniform LDS base + lane*16, per-lane src)
// =====================================================================
__device__ __forceinline__ void gl_lds16(const void* g, void* l) {
    __builtin_amdgcn_global_load_lds(
        (const __attribute__((address_space(1))) unsigned int*)g,
        (__attribute__((address_space(3))) unsigned int*)l,
        16, 0, 0);
}

__device__ __forceinline__ unsigned short f2bf_rne(float f) {
    unsigned u = __float_as_uint(f);
    unsigned r = u + 0x7fffu + ((u >> 16) & 1u);
    return (unsigned short)(r >> 16);
}
__device__ __forceinline__ float bf2f(unsigned short h) {
    return __uint_as_float(((unsigned)h) << 16);
}

// =====================================================================
// pack: fp32 [rows][256] -> hi/lo bf16 in MFMA-fragment-linear tiles.
// chunk c = (T*8 + s)*8 + fi holds 64 lanes x 8 bf16:
//   lane l = q*16 + rr -> element (row = T*128 + fi*16 + rr, k = s*32 + q*8 + e)
// one thread per 8-element piece.
// =====================================================================
__global__ void pack_kernel(const float* __restrict__ src,
                            us8* __restrict__ hi, us8* __restrict__ lo) {
    int idx = blockIdx.x * 256 + threadIdx.x;
    int r = idx >> 5, p = idx & 31;
    const float4* s4 = reinterpret_cast<const float4*>(src + ((size_t)r << 8) + p * 8);
    float4 x0 = s4[0], x1 = s4[1];
    float f[8] = {x0.x, x0.y, x0.z, x0.w, x1.x, x1.y, x1.z, x1.w};
    us8 h, l;
    #pragma unroll
    for (int e = 0; e < 8; ++e) {
        unsigned short hb = f2bf_rne(f[e]);
        h[e] = hb;
        l[e] = f2bf_rne(f[e] - bf2f(hb));
    }
    int T = r >> 7, fi = (r >> 4) & 7, rr = r & 15, s = p >> 2, q = p & 3;
    size_t unit = ((size_t)((T * 8 + s) * 8 + fi)) * 64 + q * 16 + rr;
    hi[unit] = h;
    lo[unit] = l;
}

// =====================================================================
// row squared-norms (fp32 input). one wave per row, 4 rows per block.
// =====================================================================
__global__ void rownorm_kernel(const float* __restrict__ src,
                               float* __restrict__ dst) {
    int wave = threadIdx.x >> 6;
    int lane = threadIdx.x & 63;
    int row  = blockIdx.x * 4 + wave;
    const float4 v = *reinterpret_cast<const float4*>(&src[(size_t)row * D_DIM + lane * 4]);
    float s = v.x * v.x + v.y * v.y + v.z * v.z + v.w * v.w;
    #pragma unroll
    for (int off = 32; off; off >>= 1) s += __shfl_down(s, off, 64);
    if (lane == 0) dst[row] = s;
}

// =====================================================================
// MFMA GEMM + fused argmin.
// 128x128 tile, 4 waves (2x2), 16x16x32 bf16, 4x4 frags/wave.
// 3 MFMAs per frag pair: hi*hi + hi*lo + lo*hi.
// Double-buffered LDS (2 x 32KB), one barrier per K-step.
// Each block loops 8 N-tiles (grid.y selects a band of 8), folding
// argmin in registers; final u64 atomicMin per row.
// LDS buffer layout: [A_hi 8K][A_lo 8K][B_hi 8K][B_lo 8K]; wave w stages
// region w of next buffer (w0=A_hi, w1=A_lo, w2=B_hi, w3=B_lo).
// =====================================================================
__launch_bounds__(256, 2)
__global__ void gemm_argmin(const us8* __restrict__ zH, const us8* __restrict__ zL,
                            const us8* __restrict__ eH, const us8* __restrict__ eL,
                            const float* __restrict__ znorm,
                            const float* __restrict__ enorm,
                            unsigned long long* __restrict__ best) {
    __shared__ char lds[65536];
    const int t  = threadIdx.x;
    const int l  = t & 63;
    const int w  = t >> 6;
    const int mt = blockIdx.x;          // 0..127
    const int nb = blockIdx.y;          // 0..7 (band of 8 n-tiles)
    const int wr = w >> 1, wc = w & 1;
    const int lg = l >> 4, lr = l & 15;

    const char* garr = (const char*)((w == 0) ? zH : (w == 1) ? zL : (w == 2) ? eH : eL);

    // ---- staging: wave w loads its 8 chunks (8KB) of (tile, s) ----
    auto stage = [&](int nt_i, int s, int buf) {
        const int tile = (w < 2) ? mt : (nb * 8 + nt_i);
        const char* src = garr + (size_t)tile * 65536 + (size_t)s * 8192 + (size_t)l * 16;
        char* dst = lds + buf * 32768 + w * 8192;
        #pragma unroll
        for (int u = 0; u < 8; ++u)
            gl_lds16(src + u * 1024, dst + u * 1024);
    };

    // znorm for this lane's 16 rows (independent of nt)
    const int m_base = mt * 128 + wr * 64;
    float zn[4][4];
    #pragma unroll
    for (int i = 0; i < 4; ++i)
        #pragma unroll
        for (int r = 0; r < 4; ++r)
            zn[i][r] = znorm[m_base + i * 16 + lg * 4 + r];

    float bs[4][4];
    int   bi[4][4];
    #pragma unroll
    for (int i = 0; i < 4; ++i)
        #pragma unroll
        for (int r = 0; r < 4; ++r) { bs[i][r] = 3.4e38f; bi[i][r] = 0x7fffffff; }

    stage(0, 0, 0);
    __syncthreads();

    for (int nt_i = 0; nt_i < 8; ++nt_i) {
        f32x4 acc[4][4] = {};

        for (int s = 0; s < NSTEP; ++s) {
            const int buf = s & 1;
            if (s < NSTEP - 1)      stage(nt_i, s + 1, buf ^ 1);
            else if (nt_i < 7)      stage(nt_i + 1, 0, buf ^ 1);

            const char* base = lds + buf * 32768;
            bf16x8 ah[4], al[4], bh[4], bl[4];
            #pragma unroll
            for (int i = 0; i < 4; ++i) {
                ah[i] = *(const bf16x8*)(base +     0 + (wr * 4 + i) * 1024 + l * 16);
                al[i] = *(const bf16x8*)(base +  8192 + (wr * 4 + i) * 1024 + l * 16);
                bh[i] = *(const bf16x8*)(base + 16384 + (wc * 4 + i) * 1024 + l * 16);
                bl[i] = *(const bf16x8*)(base + 24576 + (wc * 4 + i) * 1024 + l * 16);
            }

            #pragma unroll
            for (int i = 0; i < 4; ++i)
                #pragma unroll
                for (int j = 0; j < 4; ++j)
                    acc[i][j] = __builtin_amdgcn_mfma_f32_16x16x32_bf16(ah[i], bh[j], acc[i][j], 0, 0, 0);
            #pragma unroll
            for (int i = 0; i < 4; ++i)
                #pragma unroll
                for (int j = 0; j < 4; ++j)
                    acc[i][j] = __builtin_amdgcn_mfma_f32_16x16x32_bf16(ah[i], bl[j], acc[i][j], 0, 0, 0);
            #pragma unroll
            for (int i = 0; i < 4; ++i)
                #pragma unroll
                for (int j = 0; j < 4; ++j)
                    acc[i][j] = __builtin_amdgcn_mfma_f32_16x16x32_bf16(al[i], bh[j], acc[i][j], 0, 0, 0);

            if (!(s == NSTEP - 1 && nt_i == 7)) __syncthreads();
        }

        // fold this n-tile into the running per-lane best
        const int n_base = (nb * 8 + nt_i) * 128 + wc * 64;
        #pragma unroll
        for (int j = 0; j < 4; ++j) {
            const int n  = n_base + j * 16 + lr;
            const float en = enorm[n];
            #pragma unroll
            for (int i = 0; i < 4; ++i)
                #pragma unroll
                for (int r = 0; r < 4; ++r) {
                    float sc = (zn[i][r] + en) - 2.0f * acc[i][j][r];
                    if (sc < bs[i][r] || (sc == bs[i][r] && n < bi[i][r])) {
                        bs[i][r] = sc; bi[i][r] = n;
                    }
                }
        }
    }

    // reduce across the 16 lanes of each lane-group, then atomicMin
    #pragma unroll
    for (int i = 0; i < 4; ++i)
        #pragma unroll
        for (int r = 0; r < 4; ++r) {
            unsigned key = __float_as_uint(bs[i][r]);
            key = (key & 0x80000000u) ? ~key : (key | 0x80000000u);
            unsigned long long pk = ((unsigned long long)key << 32) | (unsigned)bi[i][r];
            #pragma unroll
            for (int off = 1; off < 16; off <<= 1) {
                unsigned long long o = __shfl_xor(pk, off);
                if (o < pk) pk = o;
            }
            if (lr == 0) atomicMin(&best[m_base + i * 16 + lg * 4 + r], pk);
        }
}

// =====================================================================
// per-row assignment: z_st, codes, loss partials, counts, dw
// =====================================================================
__global__ void assign_kernel(const float* __restrict__ z,
                              const float* __restrict__ emb,
                              const unsigned long long* __restrict__ best,
                              float* __restrict__ out_zst,
                              float* __restrict__ out_codes,
                              float* __restrict__ dw,
                              float* __restrict__ counts,
                              float* __restrict__ loss_arr) {
    const int n = blockIdx.x;
    const int d = threadIdx.x;
    const int idx = (int)(best[n] & 0xffffffffull);

    float zv = z[(size_t)n * D_DIM + d];
    float ev = emb[(size_t)idx * D_DIM + d];
    out_zst[(size_t)n * D_DIM + d] = zv + (ev - zv);

    float diff = ev - zv;
    float lsum = diff * diff;
    #pragma unroll
    for (int off = 32; off; off >>= 1) lsum += __shfl_down(lsum, off, 64);
    __shared__ float r4[4];
    if ((d & 63) == 0) r4[d >> 6] = lsum;
    __syncthreads();

    atomicAdd(&dw[(size_t)idx * D_DIM + d], zv);
    if (d == 0) {
        atomicAdd(&counts[idx], 1.0f);
        out_codes[n] = (float)idx;
        atomicAdd(&loss_arr[n & 127], r4[0] + r4[1] + r4[2] + r4[3]);
    }
}

__global__ void ema_cs_kernel(const float* __restrict__ ema_cs,
                              const float* __restrict__ counts,
                              float* __restrict__ out_ncs,
                              float* __restrict__ nsum) {
    const int k = blockIdx.x * 256 + threadIdx.x;
    float v = ema_cs[k] * DECAYF + OMDF * counts[k];
    out_ncs[k] = v;
    float s = v;
    #pragma unroll
    for (int off = 32; off; off >>= 1) s += __shfl_down(s, off, 64);
    __shared__ float r4[4];
    if ((threadIdx.x & 63) == 0) r4[threadIdx.x >> 6] = s;
    __syncthreads();
    if (threadIdx.x == 0) atomicAdd(nsum, r4[0] + r4[1] + r4[2] + r4[3]);
}

__global__ void finalize_kernel(const float* __restrict__ ema_w,
                                const float* __restrict__ dw,
                                const float* __restrict__ out_ncs,
                                const float* __restrict__ nsum,
                                const float* __restrict__ loss_arr,
                                float* __restrict__ out_emb,
                                float* __restrict__ out_emaw,
                                float* __restrict__ out_loss) {
    const int k = blockIdx.x;
    const int d = threadIdx.x;
    const float n   = *nsum;
    const float ncs = out_ncs[k];
    const float cs  = (ncs + EPSF) / (n + (float)K_EMB * EPSF) * n;
    const size_t o  = (size_t)k * D_DIM + d;
    float w = ema_w[o] * DECAYF + OMDF * dw[o];
    out_emaw[o] = w;
    out_emb[o]  = w / cs;
    if (k == 0 && d == 0) {
        float s = 0.f;
        #pragma unroll
        for (int i = 0; i < 128; ++i) s += loss_arr[i];
        *out_loss = CCOST * s / (float)((size_t)N_ROWS * D_DIM);
    }
}

// =====================================================================
extern "C" void kernel_launch(void* const* d_in, const int* in_sizes, int n_in,
                              void* d_out, int out_size, void* d_ws, size_t ws_size,
                              hipStream_t stream) {
    const float* z      = (const float*)d_in[0];
    const float* emb    = (const float*)d_in[1];
    const float* ema_cs = (const float*)d_in[2];
    const float* ema_w  = (const float*)d_in[3];
    float* out = (float*)d_out;

    char* ws = (char*)d_ws;
    unsigned long long* best = (unsigned long long*)(ws + OFF_PACKED);
    float* counts   = (float*)(ws + OFF_COUNTS);
    float* enorm    = (float*)(ws + OFF_ENORM);
    float* nsum     = (float*)(ws + OFF_NSUM);
    float* loss_arr = (float*)(ws + OFF_LOSSA);
    float* znorm    = (float*)(ws + OFF_ZNORM);
    us8*   zH       = (us8*)(ws + OFF_ZH);
    us8*   zL       = (us8*)(ws + OFF_ZL);
    us8*   eH       = (us8*)(ws + OFF_EH);
    us8*   eL       = (us8*)(ws + OFF_EL);
    float* dw       = (float*)(ws + OFF_DW);   // aliases zH; zeroed after GEMM

    hipMemsetAsync(ws + OFF_PACKED, 0xFF, 131072, stream);            // best = u64 max
    hipMemsetAsync(ws + OFF_COUNTS, 0, OFF_ZNORM - OFF_COUNTS, stream); // counts/nsum/loss

    pack_kernel<<<N_ROWS * 32 / 256, 256, 0, stream>>>(z, zH, zL);
    pack_kernel<<<K_EMB * 32 / 256, 256, 0, stream>>>(emb, eH, eL);
    rownorm_kernel<<<N_ROWS / 4, 256, 0, stream>>>(z, znorm);
    rownorm_kernel<<<K_EMB / 4, 256, 0, stream>>>(emb, enorm);

    dim3 grid_g(N_ROWS / 128, K_EMB / (128 * 8));   // (128, 8)
    gemm_argmin<<<grid_g, 256, 0, stream>>>(zH, zL, eH, eL, znorm, enorm, best);

    // dw aliases zH: zero it only after the GEMM has consumed zH
    hipMemsetAsync(ws + OFF_DW, 0, 8388608, stream);

    assign_kernel<<<N_ROWS, 256, 0, stream>>>(
        z, emb, best, out + O_ZST, out + O_CODE, dw, counts, loss_arr);

    ema_cs_kernel<<<K_EMB / 256, 256, 0, stream>>>(ema_cs, counts,
                                                   out + O_NCS, nsum);

    finalize_kernel<<<K_EMB, 256, 0, stream>>>(
        ema_w, dw, out + O_NCS, nsum, loss_arr,
        out + O_EMB, out + O_EMAW, out + O_LOSS);
}

// Round 13
// 364.660 us; speedup vs baseline: 3.6696x; 1.0075x over previous
//
#include <hip/hip_runtime.h>
#include <hip/hip_bf16.h>
#include <stdint.h>

#define K_EMB 8192
#define D_DIM 256
#define N_ROWS 16384          // 8*2048
#define DECAYF 0.99f
#define OMDF 0.01f
#define EPSF 1e-5f
#define CCOST 0.25f
#define NSTEP 8               // 256 / 32

// ---- workspace byte offsets (round-7 layout, verified) ----
#define OFF_PACKED 0u                    // u64[16384]  = 131072 B
#define OFF_COUNTS 131072u               // f32[8192]
#define OFF_ENORM  163840u               // f32[8192]
#define OFF_NSUM   196608u               // f32[1] (+pad)
#define OFF_LOSSA  196864u               // f32[128] (+pad)
#define OFF_ZNORM  197376u               // f32[16384]
#define OFF_ZH     262912u               // bf16 packed 8 MB (aliases dw after GEMM)
#define OFF_DW     262912u               // f32[8192*256] 8 MB (alias of ZH)
#define OFF_ZL     8651520u              // 8 MB
#define OFF_EH     17040128u             // 4 MB
#define OFF_EL     21234432u             // 4 MB
// total ws need: 25428736 B

// ---- output float offsets (outputs concatenated flat, fp32) ----
#define O_ZST  0
#define O_LOSS 4194304
#define O_CODE 4194305
#define O_EMB  4210689
#define O_NCS  6307841
#define O_EMAW 6316033

typedef __bf16 bf16x8 __attribute__((ext_vector_type(8)));
typedef float  f32x4  __attribute__((ext_vector_type(4)));
typedef unsigned short us8 __attribute__((ext_vector_type(8)));

// =====================================================================
// async global->LDS 16B (wave-uniform LDS base + lane*16, per-lane src)
// =====================================================================
__device__ __forceinline__ void gl_lds16(const void* g, void* l) {
    __builtin_amdgcn_global_load_lds(
        (const __attribute__((address_space(1))) unsigned int*)g,
        (__attribute__((address_space(3))) unsigned int*)l,
        16, 0, 0);
}
__device__ __forceinline__ unsigned short f2bf_rne(float f) {
    unsigned u = __float_as_uint(f);
    unsigned r = u + 0x7fffu + ((u >> 16) & 1u);
    return (unsigned short)(r >> 16);
}
__device__ __forceinline__ float bf2f(unsigned short h) {
    return __uint_as_float(((unsigned)h) << 16);
}

// =====================================================================
// pack + norms fused, BOTH tensors in one launch.
// rows [0,16384) = z -> zH/zL/znorm; rows [16384,24576) = emb -> eH/eL/enorm.
// fp32 [rows][256] -> hi/lo bf16 in MFMA-fragment-linear tiles (r7 layout):
// chunk c = (T*8 + s)*8 + fi holds 64 lanes x 8 bf16:
//   lane l = q*16 + rr -> element (row = T*128 + fi*16 + rr, k = s*32 + q*8 + e)
// 32 threads per row; width-32 shuffle reduce for the row norm.
// =====================================================================
__launch_bounds__(256)
__global__ void pack_norm_all(const float* __restrict__ z,
                              const float* __restrict__ emb,
                              us8* __restrict__ zh, us8* __restrict__ zl,
                              us8* __restrict__ eh, us8* __restrict__ el,
                              float* __restrict__ znorm,
                              float* __restrict__ enorm) {
    int idx = blockIdx.x * 256 + threadIdx.x;
    int r = idx >> 5, p = idx & 31;
    const bool isz = (r < N_ROWS);
    const float* src = isz ? z : emb;
    const int rr = isz ? r : (r - N_ROWS);
    const float4* s4 = reinterpret_cast<const float4*>(src + ((size_t)rr << 8) + p * 8);
    float4 x0 = s4[0], x1 = s4[1];
    float f[8] = {x0.x, x0.y, x0.z, x0.w, x1.x, x1.y, x1.z, x1.w};
    us8 h, l;
    float sn = 0.f;
    #pragma unroll
    for (int e = 0; e < 8; ++e) {
        unsigned short hb = f2bf_rne(f[e]);
        h[e] = hb;
        l[e] = f2bf_rne(f[e] - bf2f(hb));
        sn = fmaf(f[e], f[e], sn);
    }
    int T = rr >> 7, fi = (rr >> 4) & 7, rq = rr & 15, s = p >> 2, q = p & 3;
    size_t unit = ((size_t)((T * 8 + s) * 8 + fi)) * 64 + q * 16 + rq;
    if (isz) { zh[unit] = h; zl[unit] = l; }
    else     { eh[unit] = h; el[unit] = l; }
    #pragma unroll
    for (int off = 16; off; off >>= 1) sn += __shfl_down(sn, off, 32);
    if (p == 0) { if (isz) znorm[rr] = sn; else enorm[rr] = sn; }
}

// =====================================================================
// MFMA GEMM + fused argmin (round-7 verbatim).
// 128x128 tile, 4 waves (2x2), 16x16x32 bf16, 4x4 frags/wave.
// 3 MFMAs per frag pair: hi*hi + hi*lo + lo*hi.
// Double-buffered LDS (2 x 32KB), one barrier per K-step.
// Each block loops 8 N-tiles (grid.y selects a band of 8), folding
// argmin in registers; final u64 atomicMin per row.
// =====================================================================
__launch_bounds__(256, 2)
__global__ void gemm_argmin(const us8* __restrict__ zH, const us8* __restrict__ zL,
                            const us8* __restrict__ eH, const us8* __restrict__ eL,
                            const float* __restrict__ znorm,
                            const float* __restrict__ enorm,
                            unsigned long long* __restrict__ best) {
    __shared__ __align__(16) char lds[65536];
    const int t  = threadIdx.x;
    const int l  = t & 63;
    const int w  = t >> 6;
    const int mt = blockIdx.x;          // 0..127
    const int nb = blockIdx.y;          // 0..7 (band of 8 n-tiles)
    const int wr = w >> 1, wc = w & 1;
    const int lg = l >> 4, lr = l & 15;

    const char* garr = (const char*)((w == 0) ? zH : (w == 1) ? zL : (w == 2) ? eH : eL);

    auto stage = [&](int nt_i, int s, int buf) {
        const int tile = (w < 2) ? mt : (nb * 8 + nt_i);
        const char* src = garr + (size_t)tile * 65536 + (size_t)s * 8192 + (size_t)l * 16;
        char* dst = lds + buf * 32768 + w * 8192;
        #pragma unroll
        for (int u = 0; u < 8; ++u)
            gl_lds16(src + u * 1024, dst + u * 1024);
    };

    const int m_base = mt * 128 + wr * 64;
    float zn[4][4];
    #pragma unroll
    for (int i = 0; i < 4; ++i)
        #pragma unroll
        for (int r = 0; r < 4; ++r)
            zn[i][r] = znorm[m_base + i * 16 + lg * 4 + r];

    float bs[4][4];
    int   bi[4][4];
    #pragma unroll
    for (int i = 0; i < 4; ++i)
        #pragma unroll
        for (int r = 0; r < 4; ++r) { bs[i][r] = 3.4e38f; bi[i][r] = 0x7fffffff; }

    stage(0, 0, 0);
    __syncthreads();

    for (int nt_i = 0; nt_i < 8; ++nt_i) {
        f32x4 acc[4][4] = {};

        for (int s = 0; s < NSTEP; ++s) {
            const int buf = s & 1;
            if (s < NSTEP - 1)      stage(nt_i, s + 1, buf ^ 1);
            else if (nt_i < 7)      stage(nt_i + 1, 0, buf ^ 1);

            const char* base = lds + buf * 32768;
            bf16x8 ah[4], al[4], bh[4], bl[4];
            #pragma unroll
            for (int i = 0; i < 4; ++i) {
                ah[i] = *(const bf16x8*)(base +     0 + (wr * 4 + i) * 1024 + l * 16);
                al[i] = *(const bf16x8*)(base +  8192 + (wr * 4 + i) * 1024 + l * 16);
                bh[i] = *(const bf16x8*)(base + 16384 + (wc * 4 + i) * 1024 + l * 16);
                bl[i] = *(const bf16x8*)(base + 24576 + (wc * 4 + i) * 1024 + l * 16);
            }

            #pragma unroll
            for (int i = 0; i < 4; ++i)
                #pragma unroll
                for (int j = 0; j < 4; ++j)
                    acc[i][j] = __builtin_amdgcn_mfma_f32_16x16x32_bf16(ah[i], bh[j], acc[i][j], 0, 0, 0);
            #pragma unroll
            for (int i = 0; i < 4; ++i)
                #pragma unroll
                for (int j = 0; j < 4; ++j)
                    acc[i][j] = __builtin_amdgcn_mfma_f32_16x16x32_bf16(ah[i], bl[j], acc[i][j], 0, 0, 0);
            #pragma unroll
            for (int i = 0; i < 4; ++i)
                #pragma unroll
                for (int j = 0; j < 4; ++j)
                    acc[i][j] = __builtin_amdgcn_mfma_f32_16x16x32_bf16(al[i], bh[j], acc[i][j], 0, 0, 0);

            if (!(s == NSTEP - 1 && nt_i == 7)) __syncthreads();
        }

        const int n_base = (nb * 8 + nt_i) * 128 + wc * 64;
        #pragma unroll
        for (int j = 0; j < 4; ++j) {
            const int n  = n_base + j * 16 + lr;
            const float en = enorm[n];
            #pragma unroll
            for (int i = 0; i < 4; ++i)
                #pragma unroll
                for (int r = 0; r < 4; ++r) {
                    float sc = (zn[i][r] + en) - 2.0f * acc[i][j][r];
                    if (sc < bs[i][r] || (sc == bs[i][r] && n < bi[i][r])) {
                        bs[i][r] = sc; bi[i][r] = n;
                    }
                }
        }
    }

    #pragma unroll
    for (int i = 0; i < 4; ++i)
        #pragma unroll
        for (int r = 0; r < 4; ++r) {
            unsigned key = __float_as_uint(bs[i][r]);
            key = (key & 0x80000000u) ? ~key : (key | 0x80000000u);
            unsigned long long pk = ((unsigned long long)key << 32) | (unsigned)bi[i][r];
            #pragma unroll
            for (int off = 1; off < 16; off <<= 1) {
                unsigned long long o = __shfl_xor(pk, off);
                if (o < pk) pk = o;
            }
            if (lr == 0) atomicMin(&best[m_base + i * 16 + lg * 4 + r], pk);
        }
}

// =====================================================================
// per-row assignment: z_st, codes, loss partials, counts, dw (r7 verbatim)
// =====================================================================
__global__ void assign_kernel(const float* __restrict__ z,
                              const float* __restrict__ emb,
                              const unsigned long long* __restrict__ best,
                              float* __restrict__ out_zst,
                              float* __restrict__ out_codes,
                              float* __restrict__ dw,
                              float* __restrict__ counts,
                              float* __restrict__ loss_arr) {
    const int n = blockIdx.x;
    const int d = threadIdx.x;
    const int idx = (int)(best[n] & 0xffffffffull);

    float zv = z[(size_t)n * D_DIM + d];
    float ev = emb[(size_t)idx * D_DIM + d];
    out_zst[(size_t)n * D_DIM + d] = zv + (ev - zv);

    float diff = ev - zv;
    float lsum = diff * diff;
    #pragma unroll
    for (int off = 32; off; off >>= 1) lsum += __shfl_down(lsum, off, 64);
    __shared__ float r4[4];
    if ((d & 63) == 0) r4[d >> 6] = lsum;
    __syncthreads();

    atomicAdd(&dw[(size_t)idx * D_DIM + d], zv);
    if (d == 0) {
        atomicAdd(&counts[idx], 1.0f);
        out_codes[n] = (float)idx;
        atomicAdd(&loss_arr[n & 127], r4[0] + r4[1] + r4[2] + r4[3]);
    }
}

__global__ void ema_cs_kernel(const float* __restrict__ ema_cs,
                              const float* __restrict__ counts,
                              float* __restrict__ out_ncs,
                              float* __restrict__ nsum) {
    const int k = blockIdx.x * 256 + threadIdx.x;
    float v = ema_cs[k] * DECAYF + OMDF * counts[k];
    out_ncs[k] = v;
    float s = v;
    #pragma unroll
    for (int off = 32; off; off >>= 1) s += __shfl_down(s, off, 64);
    __shared__ float r4[4];
    if ((threadIdx.x & 63) == 0) r4[threadIdx.x >> 6] = s;
    __syncthreads();
    if (threadIdx.x == 0) atomicAdd(nsum, r4[0] + r4[1] + r4[2] + r4[3]);
}

__global__ void finalize_kernel(const float* __restrict__ ema_w,
                                const float* __restrict__ dw,
                                const float* __restrict__ out_ncs,
                                const float* __restrict__ nsum,
                                const float* __restrict__ loss_arr,
                                float* __restrict__ out_emb,
                                float* __restrict__ out_emaw,
                                float* __restrict__ out_loss) {
    const int k = blockIdx.x;
    const int d = threadIdx.x;
    const float n   = *nsum;
    const float ncs = out_ncs[k];
    const float cs  = (ncs + EPSF) / (n + (float)K_EMB * EPSF) * n;
    const size_t o  = (size_t)k * D_DIM + d;
    float w = ema_w[o] * DECAYF + OMDF * dw[o];
    out_emaw[o] = w;
    out_emb[o]  = w / cs;
    if (k == 0 && d == 0) {
        float s = 0.f;
        #pragma unroll
        for (int i = 0; i < 128; ++i) s += loss_arr[i];
        *out_loss = CCOST * s / (float)((size_t)N_ROWS * D_DIM);
    }
}

// =====================================================================
extern "C" void kernel_launch(void* const* d_in, const int* in_sizes, int n_in,
                              void* d_out, int out_size, void* d_ws, size_t ws_size,
                              hipStream_t stream) {
    const float* z      = (const float*)d_in[0];
    const float* emb    = (const float*)d_in[1];
    const float* ema_cs = (const float*)d_in[2];
    const float* ema_w  = (const float*)d_in[3];
    float* out = (float*)d_out;

    char* ws = (char*)d_ws;
    unsigned long long* best = (unsigned long long*)(ws + OFF_PACKED);
    float* counts   = (float*)(ws + OFF_COUNTS);
    float* enorm    = (float*)(ws + OFF_ENORM);
    float* nsum     = (float*)(ws + OFF_NSUM);
    float* loss_arr = (float*)(ws + OFF_LOSSA);
    float* znorm    = (float*)(ws + OFF_ZNORM);
    us8*   zH       = (us8*)(ws + OFF_ZH);
    us8*   zL       = (us8*)(ws + OFF_ZL);
    us8*   eH       = (us8*)(ws + OFF_EH);
    us8*   eL       = (us8*)(ws + OFF_EL);
    float* dw       = (float*)(ws + OFF_DW);   // aliases zH; zeroed after GEMM

    hipMemsetAsync(ws + OFF_PACKED, 0xFF, 131072, stream);              // best = u64 max
    hipMemsetAsync(ws + OFF_COUNTS, 0, OFF_ZNORM - OFF_COUNTS, stream); // counts/nsum/loss

    // one fused launch: packs both tensors + both row-norm arrays
    pack_norm_all<<<(N_ROWS + K_EMB) * 32 / 256, 256, 0, stream>>>(
        z, emb, zH, zL, eH, eL, znorm, enorm);

    dim3 grid_g(N_ROWS / 128, K_EMB / (128 * 8));   // (128, 8)
    gemm_argmin<<<grid_g, 256, 0, stream>>>(zH, zL, eH, eL, znorm, enorm, best);

    // dw aliases zH: zero it only after the GEMM has consumed zH
    hipMemsetAsync(ws + OFF_DW, 0, 8388608, stream);

    assign_kernel<<<N_ROWS, 256, 0, stream>>>(
        z, emb, best, out + O_ZST, out + O_CODE, dw, counts, loss_arr);

    ema_cs_kernel<<<K_EMB / 256, 256, 0, stream>>>(ema_cs, counts,
                                                   out + O_NCS, nsum);

    finalize_kernel<<<K_EMB, 256, 0, stream>>>(
        ema_w, dw, out + O_NCS, nsum, loss_arr,
        out + O_EMB, out + O_EMAW, out + O_LOSS);
}